// Round 3
// baseline (174.098 us; speedup 1.0000x reference)
//
#include <hip/hip_runtime.h>
#include <math.h>

#define HH 480
#define WW 640
#define HW (HH*WW)

// ---------------- K1: horizontal resample + p maps ----------------

__device__ __forceinline__ float sample1(const float* __restrict__ row, float x) {
    float x0 = floorf(x);
    float w1 = x - x0;
    int xi = (int)x0;
    float v0 = (xi >= 0 && xi < WW) ? row[xi] : 0.f;
    float v1 = (xi + 1 >= 0 && xi + 1 < WW) ? row[xi + 1] : 0.f;
    return v0 * (1.f - w1) + v1 * w1;
}

__global__ __launch_bounds__(256) void k_resample(
    const float* __restrict__ left, const float* __restrict__ right,
    const float* __restrict__ dispL, const float* __restrict__ dispR,
    float* __restrict__ rir, float* __restrict__ ril,
    float* __restrict__ pL, float* __restrict__ pR)
{
    int idx = blockIdx.x * blockDim.x + threadIdx.x;
    if (idx >= HW) return;
    int h = idx / WW;
    int w = idx - h * WW;
    float dL = dispL[idx];
    float dR = dispR[idx];
    float xl = (float)w - dL;   // sample right view at j - dispL
    float xr = (float)w + dR;   // sample left view  at j + dispR
    #pragma unroll
    for (int c = 0; c < 3; ++c) {
        rir[c*HW + idx] = sample1(right + c*HW + h*WW, xl);
        ril[c*HW + idx] = sample1(left  + c*HW + h*WW, xr);
    }
    float rdr = sample1(dispR + h*WW, xl);
    float rdl = sample1(dispL + h*WW, xr);
    pL[idx] = __expf(-0.6931f * fabsf(dL - rdr));
    pR[idx] = __expf(-0.6931f * fabsf(dR - rdl));
}

// ---------------- K2: 9x9 LCN (separable) + cost, one side per blockIdx.z ----------------
// block 32x8, tile rows 16 (8+2*4), cols 40 (32+2*4)

__global__ __launch_bounds__(256) void k_lcncost(
    const float* __restrict__ left, const float* __restrict__ right,
    const float* __restrict__ rir, const float* __restrict__ ril,
    float* __restrict__ costL, float* __restrict__ costR)
{
    __shared__ float raw[6][16][40];   // 15360 B
    __shared__ float hs [6][16][32];   // 12288 B
    __shared__ float hs2[6][16][32];   // 12288 B
    int tx = threadIdx.x, ty = threadIdx.y;
    int tid = ty * 32 + tx;
    int gx0 = blockIdx.x * 32, gy0 = blockIdx.y * 8;
    const float* __restrict__ imgA = blockIdx.z ? right : left;   // real image (std source)
    const float* __restrict__ imgB = blockIdx.z ? ril   : rir;    // reconstruction
    float* __restrict__ out = blockIdx.z ? costR : costL;

    for (int e = tid; e < 6*16*40; e += 256) {
        int a   = e / (16*40);
        int rem = e - a * (16*40);
        int r   = rem / 40;
        int x   = rem - r * 40;
        int gy = gy0 + r - 4, gx = gx0 + x - 4;
        float v = 0.f;
        if ((unsigned)gy < (unsigned)HH && (unsigned)gx < (unsigned)WW) {
            const float* s = (a < 3) ? imgA : imgB;
            int ch = (a < 3) ? a : a - 3;
            v = s[ch*HW + gy*WW + gx];
        }
        ((float*)raw)[e] = v;
    }
    __syncthreads();

    for (int e = tid; e < 6*16*32; e += 256) {
        int a   = e / (16*32);
        int rem = e - a * (16*32);
        int r   = rem / 32;
        int x   = rem - r * 32;
        float s = 0.f, s2 = 0.f;
        #pragma unroll
        for (int dx = 0; dx < 9; ++dx) {
            float v = raw[a][r][x + dx];
            s += v;
            s2 = fmaf(v, v, s2);
        }
        ((float*)hs)[e]  = s;
        ((float*)hs2)[e] = s2;
    }
    __syncthreads();

    int idx = (gy0 + ty) * WW + gx0 + tx;
    #pragma unroll
    for (int c = 0; c < 3; ++c) {
        float SA = 0.f, SA2 = 0.f, SB = 0.f, SB2 = 0.f;
        #pragma unroll
        for (int dy = 0; dy < 9; ++dy) {
            SA  += hs [c][ty + dy][tx];
            SA2 += hs2[c][ty + dy][tx];
            SB  += hs [3 + c][ty + dy][tx];
            SB2 += hs2[3 + c][ty + dy][tx];
        }
        float meanA = SA * (1.f/81.f);
        float stdA  = sqrtf(fmaxf(SA2 * (1.f/81.f) - meanA * meanA, 0.f)) * (81.f/80.f);
        float lcnA  = (raw[c][ty + 4][tx + 4] - meanA) / (stdA + 1e-5f);
        float meanB = SB * (1.f/81.f);
        float stdB  = sqrtf(fmaxf(SB2 * (1.f/81.f) - meanB * meanB, 0.f)) * (81.f/80.f);
        float lcnB  = (raw[3 + c][ty + 4][tx + 4] - meanB) / (stdB + 1e-5f);
        out[c*HW + idx] = fabsf((lcnA - lcnB) * stdA);
    }
}

// ---------------- K3: 12x12 ASW + losses + reduction, 2x2 outputs/thread ----------------
// block (16,8) = 128 threads -> 32x16 output region.
// tile: x-parity-split float4 (guide, costL, costR, 0):
//   tile[p][c][r][xi] holds tile-col x = 2*xi + p, row r = gy0 + r - 6, col gx0 + x - 6.
// Thread (tx,ty) computes outputs (2tx+j, 2ty+i), window tile rows 2ty+dy (dy 0..12),
// cols 2tx+dx (dx 0..12); eligibility: output i taps dy-i in 0..11, output j taps dx-j in 0..11.

#define T3R 27
#define T3XH 22

__global__ __launch_bounds__(128) void k_asw_reduce(
    const float* __restrict__ left, const float* __restrict__ right,
    const float* __restrict__ rir, const float* __restrict__ ril,
    const float* __restrict__ costL, const float* __restrict__ costR,
    const float* __restrict__ pL, const float* __restrict__ pR,
    float* __restrict__ acc)
{
    __shared__ float4 tile[2][3][T3R][T3XH];   // 57024 B
    __shared__ float red[2][6];
    int tx = threadIdx.x, ty = threadIdx.y;
    int tid = ty * 16 + tx;
    int gx0 = blockIdx.x * 32, gy0 = blockIdx.y * 16;

    for (int e = tid; e < 3 * T3R * 43; e += 128) {
        int c   = e / (T3R * 43);
        int rem = e - c * (T3R * 43);
        int r   = rem / 43;
        int x   = rem - r * 43;
        int gy = gy0 + r - 6, gx = gx0 + x - 6;
        float4 v = make_float4(0.f, 0.f, 0.f, 0.f);
        if ((unsigned)gy < (unsigned)HH && (unsigned)gx < (unsigned)WW) {
            int o = c*HW + gy*WW + gx;
            v.x = left[o];
            v.y = costL[o];
            v.z = costR[o];
        }
        tile[x & 1][c][r][x >> 1] = v;
    }
    __syncthreads();

    int ty2 = 2 * ty;
    float g[2][2][3];
    #pragma unroll
    for (int i = 0; i < 2; ++i)
        #pragma unroll
        for (int j = 0; j < 2; ++j)
            #pragma unroll
            for (int c = 0; c < 3; ++c)
                g[i][j][c] = tile[j][c][ty2 + 6 + i][tx + 3].x;

    float wg[2][2][3] = {}, aL[2][2][3] = {}, aR[2][2][3] = {};

    auto acc1 = [&](int i, int j, int c, float gx_, float cl, float cr) {
        float t = __expf(-0.5f * fabsf(g[i][j][c] - gx_));
        wg[i][j][c] += t;
        aL[i][j][c] = fmaf(t, cl, aL[i][j][c]);
        aR[i][j][c] = fmaf(t, cr, aR[i][j][c]);
    };
    auto taprow = [&](int dy, bool do0, bool do1) {
        int r = ty2 + dy;
        #pragma unroll
        for (int dx = 0; dx < 13; ++dx) {
            const bool j0 = (dx < 12), j1 = (dx > 0);
            int p  = dx & 1;
            int xi = tx + (dx >> 1);
            #pragma unroll
            for (int c = 0; c < 3; ++c) {
                float4 v = tile[p][c][r][xi];
                if (do0 && j0) acc1(0, 0, c, v.x, v.y, v.z);
                if (do0 && j1) acc1(0, 1, c, v.x, v.y, v.z);
                if (do1 && j0) acc1(1, 0, c, v.x, v.y, v.z);
                if (do1 && j1) acc1(1, 1, c, v.x, v.y, v.z);
            }
        }
    };

    taprow(0, true, false);
    for (int dy = 1; dy < 12; ++dy)   // rolled: keeps code size in I$
        taprow(dy, true, true);
    taprow(12, false, true);

    float vals[6] = {0.f, 0.f, 0.f, 0.f, 0.f, 0.f};
    #pragma unroll
    for (int i = 0; i < 2; ++i) {
        #pragma unroll
        for (int j = 0; j < 2; ++j) {
            int idx = (gy0 + ty2 + i) * WW + gx0 + 2 * tx + j;
            float sL = 0.f, sR = 0.f;
            #pragma unroll
            for (int c = 0; c < 3; ++c) {
                float aswL = aL[i][j][c] / wg[i][j][c];
                float photoL = fabsf(g[i][j][c] - rir[c*HW + idx]);
                sL += 0.5f * photoL + 0.5f * aswL;
                float aswR = aR[i][j][c] / wg[i][j][c];
                float photoR = fabsf(right[c*HW + idx] - ril[c*HW + idx]);
                sR += 0.5f * photoR + 0.5f * aswR;
            }
            float pl = pL[idx], pr = pR[idx];
            float mL = (pl > 0.5f) ? 1.f : 0.f;
            float mR = (pr > 0.5f) ? 1.f : 0.f;
            vals[0] += sL * mL;
            vals[1] += mL;
            vals[2] += sR * mR;
            vals[3] += mR;
            vals[4] += log1pf(__expf(1.f - 2.f * pl));
            vals[5] += log1pf(__expf(1.f - 2.f * pr));
        }
    }

    int lane = tid & 63, wave = tid >> 6;
    #pragma unroll
    for (int k = 0; k < 6; ++k) {
        float v = vals[k];
        #pragma unroll
        for (int off = 32; off > 0; off >>= 1) v += __shfl_down(v, off);
        if (lane == 0) red[wave][k] = v;
    }
    __syncthreads();
    if (tid == 0) {
        #pragma unroll
        for (int k = 0; k < 6; ++k)
            atomicAdd(&acc[k], red[0][k] + red[1][k]);
    }
}

// ---------------- K4: finalize ----------------

__global__ void k_final(const float* __restrict__ acc, const float* __restrict__ weight,
                        float* __restrict__ out)
{
    float S1 = acc[0], M1 = acc[1], S2 = acc[2], M2 = acc[3], C1 = acc[4], C2 = acc[5];
    float loss_valid = S1 / (3.f * M1 + 1e-6f) + S2 / (3.f * M2 + 1e-6f);
    float loss_invalid = (C1 + C2) * (1.f / (float)HW);
    out[0] = weight[0] * (0.9f * loss_valid + 0.1f * loss_invalid);
}

// ---------------- launch ----------------

extern "C" void kernel_launch(void* const* d_in, const int* in_sizes, int n_in,
                              void* d_out, int out_size, void* d_ws, size_t ws_size,
                              hipStream_t stream)
{
    const float* left  = (const float*)d_in[0];
    const float* right = (const float*)d_in[1];
    const float* dispL = (const float*)d_in[2];
    const float* dispR = (const float*)d_in[3];
    // d_in[4] = dispmap_gt (unused), d_in[5] = brk (unused)
    const float* weight = (const float*)d_in[6];

    float* ws    = (float*)d_ws;
    float* acc   = ws;              // 8 floats (6 used)
    float* rir   = ws + 8;          // 3*HW
    float* ril   = rir + 3*HW;      // 3*HW
    float* pL    = ril + 3*HW;      // HW
    float* pR    = pL + HW;         // HW
    float* costL = pR + HW;         // 3*HW
    float* costR = costL + 3*HW;    // 3*HW

    hipMemsetAsync(acc, 0, 8 * sizeof(float), stream);

    k_resample<<<(HW + 255) / 256, 256, 0, stream>>>(left, right, dispL, dispR, rir, ril, pL, pR);

    dim3 blk2(32, 8);
    dim3 grd2(WW / 32, HH / 8, 2);
    k_lcncost<<<grd2, blk2, 0, stream>>>(left, right, rir, ril, costL, costR);

    dim3 blk3(16, 8);
    dim3 grd3(WW / 32, HH / 16);
    k_asw_reduce<<<grd3, blk3, 0, stream>>>(left, right, rir, ril, costL, costR, pL, pR, acc);

    k_final<<<1, 1, 0, stream>>>(acc, weight, (float*)d_out);
}

// Round 4
// 153.479 us; speedup vs baseline: 1.1343x; 1.1343x over previous
//
#include <hip/hip_runtime.h>
#include <math.h>

#define HH 480
#define WW 640
#define HW (HH*WW)

// ---------------- K1: horizontal resample + p maps ----------------

__device__ __forceinline__ float sample1(const float* __restrict__ row, float x) {
    float x0 = floorf(x);
    float w1 = x - x0;
    int xi = (int)x0;
    float v0 = (xi >= 0 && xi < WW) ? row[xi] : 0.f;
    float v1 = (xi + 1 >= 0 && xi + 1 < WW) ? row[xi + 1] : 0.f;
    return v0 * (1.f - w1) + v1 * w1;
}

__global__ __launch_bounds__(256) void k_resample(
    const float* __restrict__ left, const float* __restrict__ right,
    const float* __restrict__ dispL, const float* __restrict__ dispR,
    float* __restrict__ rir, float* __restrict__ ril,
    float* __restrict__ pL, float* __restrict__ pR)
{
    int idx = blockIdx.x * blockDim.x + threadIdx.x;
    if (idx >= HW) return;
    int h = idx / WW;
    int w = idx - h * WW;
    float dL = dispL[idx];
    float dR = dispR[idx];
    float xl = (float)w - dL;   // sample right view at j - dispL
    float xr = (float)w + dR;   // sample left view  at j + dispR
    #pragma unroll
    for (int c = 0; c < 3; ++c) {
        rir[c*HW + idx] = sample1(right + c*HW + h*WW, xl);
        ril[c*HW + idx] = sample1(left  + c*HW + h*WW, xr);
    }
    float rdr = sample1(dispR + h*WW, xl);
    float rdl = sample1(dispL + h*WW, xr);
    pL[idx] = __expf(-0.6931f * fabsf(dL - rdr));
    pR[idx] = __expf(-0.6931f * fabsf(dR - rdl));
}

// ---------------- K2: 9x9 LCN (separable) + cost, one side per blockIdx.z ----------------
// block 32x8, tile rows 16 (8+2*4), cols 40 (32+2*4)

__global__ __launch_bounds__(256) void k_lcncost(
    const float* __restrict__ left, const float* __restrict__ right,
    const float* __restrict__ rir, const float* __restrict__ ril,
    float* __restrict__ costL, float* __restrict__ costR)
{
    __shared__ float raw[6][16][40];   // 15360 B
    __shared__ float hs [6][16][32];   // 12288 B
    __shared__ float hs2[6][16][32];   // 12288 B
    int tx = threadIdx.x, ty = threadIdx.y;
    int tid = ty * 32 + tx;
    int gx0 = blockIdx.x * 32, gy0 = blockIdx.y * 8;
    const float* __restrict__ imgA = blockIdx.z ? right : left;   // real image (std source)
    const float* __restrict__ imgB = blockIdx.z ? ril   : rir;    // reconstruction
    float* __restrict__ out = blockIdx.z ? costR : costL;

    for (int e = tid; e < 6*16*40; e += 256) {
        int a   = e / (16*40);
        int rem = e - a * (16*40);
        int r   = rem / 40;
        int x   = rem - r * 40;
        int gy = gy0 + r - 4, gx = gx0 + x - 4;
        float v = 0.f;
        if ((unsigned)gy < (unsigned)HH && (unsigned)gx < (unsigned)WW) {
            const float* s = (a < 3) ? imgA : imgB;
            int ch = (a < 3) ? a : a - 3;
            v = s[ch*HW + gy*WW + gx];
        }
        ((float*)raw)[e] = v;
    }
    __syncthreads();

    for (int e = tid; e < 6*16*32; e += 256) {
        int a   = e / (16*32);
        int rem = e - a * (16*32);
        int r   = rem / 32;
        int x   = rem - r * 32;
        float s = 0.f, s2 = 0.f;
        #pragma unroll
        for (int dx = 0; dx < 9; ++dx) {
            float v = raw[a][r][x + dx];
            s += v;
            s2 = fmaf(v, v, s2);
        }
        ((float*)hs)[e]  = s;
        ((float*)hs2)[e] = s2;
    }
    __syncthreads();

    int idx = (gy0 + ty) * WW + gx0 + tx;
    #pragma unroll
    for (int c = 0; c < 3; ++c) {
        float SA = 0.f, SA2 = 0.f, SB = 0.f, SB2 = 0.f;
        #pragma unroll
        for (int dy = 0; dy < 9; ++dy) {
            SA  += hs [c][ty + dy][tx];
            SA2 += hs2[c][ty + dy][tx];
            SB  += hs [3 + c][ty + dy][tx];
            SB2 += hs2[3 + c][ty + dy][tx];
        }
        float meanA = SA * (1.f/81.f);
        float stdA  = sqrtf(fmaxf(SA2 * (1.f/81.f) - meanA * meanA, 0.f)) * (81.f/80.f);
        float lcnA  = (raw[c][ty + 4][tx + 4] - meanA) / (stdA + 1e-5f);
        float meanB = SB * (1.f/81.f);
        float stdB  = sqrtf(fmaxf(SB2 * (1.f/81.f) - meanB * meanB, 0.f)) * (81.f/80.f);
        float lcnB  = (raw[3 + c][ty + 4][tx + 4] - meanB) / (stdB + 1e-5f);
        out[c*HW + idx] = fabsf((lcnA - lcnB) * stdA);
    }
}

// ---------------- K3: 12x12 ASW + losses + reduction ----------------
// block (32,4,3) = 384 threads = 6 waves. Thread (tx,ty,c) computes channel c of the
// 4 outputs (gx0+tx, gy0+4ty+i), i=0..3. Tile float4 = (guide, costL, costR, 0),
// rows 27 (16+11), cols 43 (32+11). Tap row for output i, window index d (0..11):
// r = 4ty + i + d  => kappa = i + d in [i, i+11]; eligible i for kappa: kappa-11..kappa.

#define T3H 27
#define T3W 43

__global__ __launch_bounds__(384) void k_asw_reduce(
    const float* __restrict__ left, const float* __restrict__ right,
    const float* __restrict__ rir, const float* __restrict__ ril,
    const float* __restrict__ costL, const float* __restrict__ costR,
    const float* __restrict__ pL, const float* __restrict__ pR,
    float* __restrict__ acc)
{
    __shared__ float4 tile[3][T3H][T3W];   // 55728 B
    __shared__ float red[6][6];
    int tx = threadIdx.x, ty = threadIdx.y, c = threadIdx.z;
    int tid = tx + 32 * ty + 128 * c;
    int gx0 = blockIdx.x * 32, gy0 = blockIdx.y * 16;

    for (int e = tid; e < 3 * T3H * T3W; e += 384) {
        int cc  = e / (T3H * T3W);
        int rem = e - cc * (T3H * T3W);
        int r   = rem / T3W;
        int x   = rem - r * T3W;
        int gy = gy0 + r - 6, gx = gx0 + x - 6;
        float4 v = make_float4(0.f, 0.f, 0.f, 0.f);
        if ((unsigned)gy < (unsigned)HH && (unsigned)gx < (unsigned)WW) {
            int o = cc*HW + gy*WW + gx;
            v.x = left[o];
            v.y = costL[o];
            v.z = costR[o];
        }
        tile[cc][r][x] = v;
    }
    __syncthreads();

    int ty4 = 4 * ty;
    float g[4];
    #pragma unroll
    for (int i = 0; i < 4; ++i) g[i] = tile[c][ty4 + i + 6][tx + 6].x;

    float wg[4] = {0.f,0.f,0.f,0.f}, aL[4] = {0.f,0.f,0.f,0.f}, aR[4] = {0.f,0.f,0.f,0.f};

    auto taprow = [&](int kap, int i0, int i1) {
        int r = ty4 + kap;
        #pragma unroll
        for (int dx = 0; dx < 12; ++dx) {
            float4 v = tile[c][r][tx + dx];
            #pragma unroll
            for (int i = 0; i < 4; ++i) {
                if (i >= i0 && i <= i1) {
                    float t = __expf(-0.5f * fabsf(g[i] - v.x));
                    wg[i] += t;
                    aL[i] = fmaf(t, v.y, aL[i]);
                    aR[i] = fmaf(t, v.z, aR[i]);
                }
            }
        }
    };

    taprow(0, 0, 0);
    taprow(1, 0, 1);
    taprow(2, 0, 2);
    for (int kap = 3; kap <= 11; ++kap)   // rolled bulk: all 4 outputs eligible
        taprow(kap, 0, 3);
    taprow(12, 1, 3);
    taprow(13, 2, 3);
    taprow(14, 3, 3);

    float vals[6] = {0.f, 0.f, 0.f, 0.f, 0.f, 0.f};
    #pragma unroll
    for (int i = 0; i < 4; ++i) {
        int idx = (gy0 + ty4 + i) * WW + gx0 + tx;
        float aswL   = aL[i] / wg[i];
        float photoL = fabsf(g[i] - rir[c*HW + idx]);
        float sLp = 0.5f * photoL + 0.5f * aswL;
        float aswR   = aR[i] / wg[i];
        float photoR = fabsf(right[c*HW + idx] - ril[c*HW + idx]);
        float sRp = 0.5f * photoR + 0.5f * aswR;
        float pl = pL[idx], pr = pR[idx];
        float mL = (pl > 0.5f) ? 1.f : 0.f;
        float mR = (pr > 0.5f) ? 1.f : 0.f;
        vals[0] += sLp * mL;
        vals[2] += sRp * mR;
        if (c == 0) {   // per-pixel terms counted once
            vals[1] += mL;
            vals[3] += mR;
            vals[4] += log1pf(__expf(1.f - 2.f * pl));
            vals[5] += log1pf(__expf(1.f - 2.f * pr));
        }
    }

    int lane = tid & 63, wave = tid >> 6;
    #pragma unroll
    for (int k = 0; k < 6; ++k) {
        float v = vals[k];
        #pragma unroll
        for (int off = 32; off > 0; off >>= 1) v += __shfl_down(v, off);
        if (lane == 0) red[wave][k] = v;
    }
    __syncthreads();
    if (tid == 0) {
        #pragma unroll
        for (int k = 0; k < 6; ++k) {
            float s = red[0][k] + red[1][k] + red[2][k] + red[3][k] + red[4][k] + red[5][k];
            atomicAdd(&acc[k], s);
        }
    }
}

// ---------------- K4: finalize ----------------

__global__ void k_final(const float* __restrict__ acc, const float* __restrict__ weight,
                        float* __restrict__ out)
{
    float S1 = acc[0], M1 = acc[1], S2 = acc[2], M2 = acc[3], C1 = acc[4], C2 = acc[5];
    float loss_valid = S1 / (3.f * M1 + 1e-6f) + S2 / (3.f * M2 + 1e-6f);
    float loss_invalid = (C1 + C2) * (1.f / (float)HW);
    out[0] = weight[0] * (0.9f * loss_valid + 0.1f * loss_invalid);
}

// ---------------- launch ----------------

extern "C" void kernel_launch(void* const* d_in, const int* in_sizes, int n_in,
                              void* d_out, int out_size, void* d_ws, size_t ws_size,
                              hipStream_t stream)
{
    const float* left  = (const float*)d_in[0];
    const float* right = (const float*)d_in[1];
    const float* dispL = (const float*)d_in[2];
    const float* dispR = (const float*)d_in[3];
    // d_in[4] = dispmap_gt (unused), d_in[5] = brk (unused)
    const float* weight = (const float*)d_in[6];

    float* ws    = (float*)d_ws;
    float* acc   = ws;              // 8 floats (6 used)
    float* rir   = ws + 8;          // 3*HW
    float* ril   = rir + 3*HW;      // 3*HW
    float* pL    = ril + 3*HW;      // HW
    float* pR    = pL + HW;         // HW
    float* costL = pR + HW;         // 3*HW
    float* costR = costL + 3*HW;    // 3*HW

    hipMemsetAsync(acc, 0, 8 * sizeof(float), stream);

    k_resample<<<(HW + 255) / 256, 256, 0, stream>>>(left, right, dispL, dispR, rir, ril, pL, pR);

    dim3 blk2(32, 8);
    dim3 grd2(WW / 32, HH / 8, 2);
    k_lcncost<<<grd2, blk2, 0, stream>>>(left, right, rir, ril, costL, costR);

    dim3 blk3(32, 4, 3);
    dim3 grd3(WW / 32, HH / 16);
    k_asw_reduce<<<grd3, blk3, 0, stream>>>(left, right, rir, ril, costL, costR, pL, pR, acc);

    k_final<<<1, 1, 0, stream>>>(acc, weight, (float*)d_out);
}